// Round 3
// baseline (433.729 us; speedup 1.0000x reference)
//
#include <hip/hip_runtime.h>

// Sinkhorn, B=8 N=1024 C=64, T=2, eps=0.1, 20 iters, scale=1e-3.
// Only batch 7 contributes (reference returns losses[-1]).
// Row/col normalize scan == diagonal scaling: u = 1/(K v), v = 1/(K^T u);
// loss = sum u_i K_ij v_j W_ij with W_ij = -0.1*log(K_ij).
//
// Persistent-kernel version: 1 init launch + 1 main launch with a hand-rolled
// device-scope barrier (cooperative launch fails under this harness, and the
// 44-launch version paid ~4.4us dispatch overhead per node -> 193us).

static constexpr int N  = 1024;
static constexpr int C  = 64;
static constexpr int NB = 128;    // blocks; << 256 CUs => co-residency guaranteed

// ws layout (floats)
static constexpr int WS_XS  = 0;          // softmax(y_s[7]/2) : 1024*64
static constexpr int WS_YS  = 65536;      // softmax(y_t[7]/2) : 1024*64
static constexpr int WS_K   = 131072;     // K    : 1024*1024
static constexpr int WS_KT  = 1179648;    // K^T  : 1024*1024
static constexpr int WS_U   = 2228224;    // u : 1024
static constexpr int WS_V   = 2229248;    // v : 1024
static constexpr int WS_P   = 2230272;    // block partials : 128
static constexpr int WS_CNT = 2230400;    // barrier counter (int)

__device__ __forceinline__ float wsum(float v) {
    #pragma unroll
    for (int o = 32; o > 0; o >>= 1) v += __shfl_down(v, o, 64);
    return v;
}
__device__ __forceinline__ float wmax(float v) {
    #pragma unroll
    for (int o = 32; o > 0; o >>= 1) v = fmaxf(v, __shfl_down(v, o, 64));
    return v;
}

// Tiny init: zero barrier counter, v := 1 (ws is poisoned 0xAA every call).
__global__ void __launch_bounds__(256)
init_k(float* __restrict__ ws)
{
    const int tid = threadIdx.x;
    if (tid == 0) *(int*)(ws + WS_CNT) = 0;
    for (int i = tid; i < N; i += 256) ws[WS_V + i] = 1.0f;
}

__global__ void __launch_bounds__(256)
sink_k(const float* __restrict__ ysrc, const float* __restrict__ ytrc,
       float* __restrict__ out, float* __restrict__ ws)
{
    __shared__ float smem[5184];   // sx 32*64 | sy 32*65 (+1 pad) | kt 32*33
    const int tid  = threadIdx.x;
    const int bid  = blockIdx.x;
    const int wid  = tid >> 6;
    const int lane = tid & 63;
    int* cnt = (int*)(ws + WS_CNT);
    int ep = 0;

    // device-scope barrier over NB blocks
    auto gbar = [&]() {
        __syncthreads();           // drains each wave's vmcnt before arrival
        ep += NB;
        if (tid == 0) {
            // RELEASE at agent scope: L2 writeback so our u/v stores reach
            // the coherence point before the arrival is visible.
            __hip_atomic_fetch_add(cnt, 1, __ATOMIC_RELEASE,
                                   __HIP_MEMORY_SCOPE_AGENT);
            int guard = 0;
            while (__hip_atomic_load(cnt, __ATOMIC_RELAXED,
                                     __HIP_MEMORY_SCOPE_AGENT) < ep) {
                __builtin_amdgcn_s_sleep(2);
                if (++guard > (1 << 22)) break;   // deadlock bailout (~2s)
            }
            __threadfence();       // acquire: invalidate stale L1/L2 lines
        }
        __syncthreads();
    };

    // ---- phase 1: softmax over N (dim=1), batch 7; one column per block ----
    {
        const float* src = ((bid < C) ? ysrc : ytrc) + 7 * N * C;
        float* dst = ws + ((bid < C) ? WS_XS : WS_YS);
        const int c = bid & (C - 1);
        float vals[4];
        float m = -1e30f;
        #pragma unroll
        for (int q = 0; q < 4; ++q) {
            vals[q] = src[(q * 256 + tid) * C + c] * 0.5f;   // y/T, T=2
            m = fmaxf(m, vals[q]);
        }
        m = wmax(m);
        if (lane == 0) smem[wid] = m;
        __syncthreads();
        m = fmaxf(fmaxf(smem[0], smem[1]), fmaxf(smem[2], smem[3]));
        float s = 0.f;
        #pragma unroll
        for (int q = 0; q < 4; ++q) { vals[q] = expf(vals[q] - m); s += vals[q]; }
        s = wsum(s);
        __syncthreads();
        if (lane == 0) smem[wid] = s;
        __syncthreads();
        s = smem[0] + smem[1] + smem[2] + smem[3];
        const float inv = 1.0f / s;
        #pragma unroll
        for (int q = 0; q < 4; ++q) dst[(q * 256 + tid) * C + c] = vals[q] * inv;
    }
    gbar();

    // ---- phase 2: K_ij = exp(-10 * sum_c |x_ic - y_jc|) and K^T ----
    {
        float* xs  = ws + WS_XS;
        float* ysm = ws + WS_YS;
        float* K   = ws + WS_K;
        float* KT  = ws + WS_KT;
        float* sx = smem;
        float* sy = smem + 2048;
        float* kt = smem + 4128;
        #pragma unroll 1
        for (int t = 0; t < 8; ++t) {              // 128 blocks x 8 tiles = 1024
            const int tt = bid * 8 + t;
            const int ti = tt >> 5, tj = tt & 31;
            __syncthreads();
            for (int k = tid; k < 2048; k += 256) sx[k] = xs[ti * 2048 + k];
            for (int k = tid; k < 2048; k += 256)
                sy[(k >> 6) * 65 + (k & 63)] = ysm[tj * 2048 + k];
            __syncthreads();
            float kv[4];
            #pragma unroll
            for (int q = 0; q < 4; ++q) {
                const int idx = q * 256 + tid;
                const int il = idx >> 5, jl = idx & 31;
                float a = 0.f;
                #pragma unroll
                for (int c = 0; c < 64; ++c)
                    a += fabsf(sx[il * 64 + c] - sy[jl * 65 + c]);
                kv[q] = expf(-10.0f * a);                       // exp(-W/eps)
                K[(ti * 32 + il) * N + tj * 32 + jl] = kv[q];
            }
            __syncthreads();
            #pragma unroll
            for (int q = 0; q < 4; ++q) {
                const int idx = q * 256 + tid;
                kt[(idx >> 5) * 33 + (idx & 31)] = kv[q];
            }
            __syncthreads();
            #pragma unroll
            for (int q = 0; q < 4; ++q) {
                const int idx = q * 256 + tid;
                const int jl = idx >> 5, il = idx & 31;
                KT[(tj * 32 + jl) * N + ti * 32 + il] = kt[il * 33 + jl];
            }
        }
    }
    gbar();

    // ---- phase 3: 20 iterations; each wave owns rows r0 and r0+512 ----
    const int r0 = bid * 4 + wid;
    const int r1 = r0 + 512;
    const float4* K4  = (const float4*)(ws + WS_K);
    const float4* KT4 = (const float4*)(ws + WS_KT);
    const float4* v4  = (const float4*)(ws + WS_V);
    const float4* u4  = (const float4*)(ws + WS_U);
    #pragma unroll 1
    for (int it = 0; it < 20; ++it) {
        float a0 = 0.f, a1 = 0.f;
        #pragma unroll
        for (int j = lane; j < 256; j += 64) {
            const float4 vv = v4[j];
            const float4 k0 = K4[r0 * 256 + j];
            const float4 k1 = K4[r1 * 256 + j];
            a0 += k0.x * vv.x + k0.y * vv.y + k0.z * vv.z + k0.w * vv.w;
            a1 += k1.x * vv.x + k1.y * vv.y + k1.z * vv.z + k1.w * vv.w;
        }
        a0 = wsum(a0); a1 = wsum(a1);
        if (lane == 0) { ws[WS_U + r0] = 1.0f / a0; ws[WS_U + r1] = 1.0f / a1; }
        gbar();
        a0 = 0.f; a1 = 0.f;
        #pragma unroll
        for (int j = lane; j < 256; j += 64) {
            const float4 uu = u4[j];
            const float4 k0 = KT4[r0 * 256 + j];
            const float4 k1 = KT4[r1 * 256 + j];
            a0 += k0.x * uu.x + k0.y * uu.y + k0.z * uu.z + k0.w * uu.w;
            a1 += k1.x * uu.x + k1.y * uu.y + k1.z * uu.z + k1.w * uu.w;
        }
        a0 = wsum(a0); a1 = wsum(a1);
        if (lane == 0) { ws[WS_V + r0] = 1.0f / a0; ws[WS_V + r1] = 1.0f / a1; }
        gbar();
    }

    // ---- phase 4: loss partials; W recovered as -0.1*log(K) ----
    {
        const float* K = ws + WS_K;
        const float* v = ws + WS_V;
        float a0 = 0.f, a1 = 0.f;
        for (int j = lane; j < N; j += 64) {
            const float k0 = K[r0 * N + j];
            const float k1 = K[r1 * N + j];
            const float vj = v[j];
            a0 += k0 * vj * logf(k0);
            a1 += k1 * vj * logf(k1);
        }
        a0 = wsum(a0); a1 = wsum(a1);
        __syncthreads();              // smem reuse
        if (lane == 0) smem[wid] = ws[WS_U + r0] * a0 + ws[WS_U + r1] * a1;
        __syncthreads();
        if (tid == 0) ws[WS_P + bid] = smem[0] + smem[1] + smem[2] + smem[3];
    }
    gbar();

    // ---- phase 5: block 0 folds the 128 partials, writes the scalar out ----
    if (bid == 0) {
        float acc = (tid < NB) ? ws[WS_P + tid] : 0.f;
        acc = wsum(acc);
        __syncthreads();
        if (lane == 0) smem[wid] = acc;
        __syncthreads();
        if (tid == 0)
            out[0] = -1e-4f * (smem[0] + smem[1] + smem[2] + smem[3]); // 1e-3*(-0.1)
    }
}

extern "C" void kernel_launch(void* const* d_in, const int* in_sizes, int n_in,
                              void* d_out, int out_size, void* d_ws, size_t ws_size,
                              hipStream_t stream) {
    const float* y_s = (const float*)d_in[0];
    const float* y_t = (const float*)d_in[1];
    float* out = (float*)d_out;
    float* ws  = (float*)d_ws;

    init_k<<<dim3(1),  dim3(256), 0, stream>>>(ws);
    sink_k<<<dim3(NB), dim3(256), 0, stream>>>(y_s, y_t, out, ws);
}

// Round 4
// 229.592 us; speedup vs baseline: 1.8891x; 1.8891x over previous
//
#include <hip/hip_runtime.h>

// Sinkhorn, B=8 N=1024 C=64, T=2, eps=0.1, 20 iters, scale=1e-3.
// Only batch 7 contributes (reference returns losses[-1]).
// Row/col normalize scan == diagonal scaling: u = 1/(K v), v = 1/(K^T u);
// loss = sum_ij u_i K_ij v_j W_ij with W_ij = -0.1*log(K_ij).
//
// Persistent kernel, RELAXED-ONLY device barrier. Round-3 lesson: agent-scope
// release/acquire fences cost ~9us each (buffer_wbl2/buffer_inv walk the whole
// L2) -> 394us. Here ALL cross-block payloads use sc0/sc1-annotated accesses
// (relaxed SYSTEM-scope atomics, coherent at the Infinity Cache), so barriers
// need no fences at all. K/KT reads stay normal cached loads (written once,
// write-through; L2 was invalidated at kernel entry, so no stale lines).

static constexpr int N  = 1024;
static constexpr int C  = 64;
static constexpr int NB = 256;   // 1 block/CU; all co-resident (256 CUs)

// ws layout (floats); harness ws is ~268 MB, we use ~8.9 MB
static constexpr int WS_XS  = 0;          // softmax(y_s[7]/2) : 1024*64
static constexpr int WS_YS  = 65536;      // softmax(y_t[7]/2) : 1024*64
static constexpr int WS_K   = 131072;     // K    : 1024*1024
static constexpr int WS_KT  = 1179648;    // K^T  : 1024*1024
static constexpr int WS_U   = 2228224;    // u : 1024
static constexpr int WS_V   = 2229248;    // v : 1024
static constexpr int WS_P   = 2230272;    // block partials : 256
static constexpr int WS_CNT = 2230528;    // int counters: root @0, leaf l @16+16*l

__device__ __forceinline__ void ast(float* p, float v) {
    __hip_atomic_store(p, v, __ATOMIC_RELAXED, __HIP_MEMORY_SCOPE_SYSTEM);
}
__device__ __forceinline__ float ald(const float* p) {
    return __hip_atomic_load(p, __ATOMIC_RELAXED, __HIP_MEMORY_SCOPE_SYSTEM);
}

__device__ __forceinline__ float wsum(float v) {
    #pragma unroll
    for (int o = 32; o > 0; o >>= 1) v += __shfl_down(v, o, 64);
    return v;
}
__device__ __forceinline__ float wmax(float v) {
    #pragma unroll
    for (int o = 32; o > 0; o >>= 1) v = fmaxf(v, __shfl_down(v, o, 64));
    return v;
}

// init: zero counters, v := 1 (ws is poisoned 0xAA before every call).
// Plain stores are fine: end-of-kernel release flushes to the coherence point.
__global__ void __launch_bounds__(256)
init_k(float* __restrict__ ws)
{
    const int tid = threadIdx.x;
    ((int*)(ws + WS_CNT))[tid] = 0;              // 256 ints covers root+leaves
    for (int i = tid; i < N; i += 256) ws[WS_V + i] = 1.0f;
}

__global__ void __launch_bounds__(256)
sink_k(const float* __restrict__ ysrc, const float* __restrict__ ytrc,
       float* __restrict__ out, float* __restrict__ ws)
{
    // sx 32*64=2048 | sy 32*68=2176 (pad->stride 68: float4-aligned, 4-way max)
    // | kt 32*33=1056  -> 5280 floats (21.1 KB)
    __shared__ float smem[5280];
    const int tid  = threadIdx.x;
    const int bid  = blockIdx.x;
    const int wid  = tid >> 6;
    const int lane = tid & 63;
    int* cbase = (int*)(ws + WS_CNT);
    int ep = 0;

    // relaxed-only two-level barrier: no release/acquire fences anywhere.
    // __syncthreads() drains vmcnt, so prior sc0sc1 payload stores are at the
    // coherence point before the arrival increment becomes visible.
    auto gbar = [&]() {
        __syncthreads();
        ++ep;
        if (tid == 0) {
            int* leaf = cbase + 16 + 16 * (bid & 7);
            int r = __hip_atomic_fetch_add(leaf, 1, __ATOMIC_RELAXED,
                                           __HIP_MEMORY_SCOPE_SYSTEM);
            if (r == ep * 32 - 1)      // last arriver of this leaf cohort
                __hip_atomic_fetch_add(cbase, 1, __ATOMIC_RELAXED,
                                       __HIP_MEMORY_SCOPE_SYSTEM);
            int guard = 0;
            while (__hip_atomic_load(cbase, __ATOMIC_RELAXED,
                                     __HIP_MEMORY_SCOPE_SYSTEM) < ep * 8) {
                __builtin_amdgcn_s_sleep(1);
                if (++guard > (1 << 22)) break;   // deadlock bailout
            }
            __atomic_signal_fence(__ATOMIC_ACQ_REL);  // compiler-only ordering
        }
        __syncthreads();
    };

    // ---- phase 1: softmax over N (dim=1), batch 7; blocks 0..127 ----
    if (bid < 2 * C) {
        const float* src = ((bid < C) ? ysrc : ytrc) + 7 * N * C;
        float* dst = ws + ((bid < C) ? WS_XS : WS_YS);
        const int c = bid & (C - 1);
        float vals[4];
        float m = -1e30f;
        #pragma unroll
        for (int q = 0; q < 4; ++q) {
            vals[q] = src[(q * 256 + tid) * C + c] * 0.5f;   // y/T, T=2
            m = fmaxf(m, vals[q]);
        }
        m = wmax(m);
        if (lane == 0) smem[wid] = m;
        __syncthreads();
        m = fmaxf(fmaxf(smem[0], smem[1]), fmaxf(smem[2], smem[3]));
        float s = 0.f;
        #pragma unroll
        for (int q = 0; q < 4; ++q) { vals[q] = expf(vals[q] - m); s += vals[q]; }
        s = wsum(s);
        __syncthreads();
        if (lane == 0) smem[wid] = s;
        __syncthreads();
        s = smem[0] + smem[1] + smem[2] + smem[3];
        const float inv = 1.0f / s;
        #pragma unroll
        for (int q = 0; q < 4; ++q)
            ast(&dst[(q * 256 + tid) * C + c], vals[q] * inv);  // write-through
    }
    gbar();

    // ---- phase 2: K_ij = exp(-10 * sum_c |x_ic - y_jc|) and K^T ----
    {
        float* xs  = ws + WS_XS;
        float* ysm = ws + WS_YS;
        float* K   = ws + WS_K;
        float* KT  = ws + WS_KT;
        float* sx = smem;          // [32][64]
        float* sy = smem + 2048;   // [32][68]
        float* kt = smem + 4224;   // [32][33]
        #pragma unroll 1
        for (int t = 0; t < 4; ++t) {
            const int tt = bid * 4 + t;
            const int ti = tt >> 5, tj = tt & 31;
            __syncthreads();
            for (int k = tid; k < 2048; k += 256) sx[k] = xs[ti * 2048 + k];
            for (int k = tid; k < 2048; k += 256)
                sy[(k >> 6) * 68 + (k & 63)] = ysm[tj * 2048 + k];
            __syncthreads();
            float kv[4];
            #pragma unroll
            for (int q = 0; q < 4; ++q) {
                const int idx = q * 256 + tid;
                const int il = idx >> 5, jl = idx & 31;
                const float4* sx4 = (const float4*)(sx + il * 64); // broadcast
                const float4* sy4 = (const float4*)(sy + jl * 68);
                float a = 0.f;
                #pragma unroll
                for (int c4 = 0; c4 < 16; ++c4) {
                    const float4 xa = sx4[c4], yb = sy4[c4];
                    a += fabsf(xa.x - yb.x) + fabsf(xa.y - yb.y)
                       + fabsf(xa.z - yb.z) + fabsf(xa.w - yb.w);
                }
                kv[q] = expf(-10.0f * a);                      // exp(-W/eps)
                ast(&K[(ti * 32 + il) * N + tj * 32 + jl], kv[q]);
            }
            __syncthreads();
            #pragma unroll
            for (int q = 0; q < 4; ++q) {
                const int idx = q * 256 + tid;
                kt[(idx >> 5) * 33 + (idx & 31)] = kv[q];
            }
            __syncthreads();
            #pragma unroll
            for (int q = 0; q < 4; ++q) {
                const int idx = q * 256 + tid;
                const int jl = idx >> 5, il = idx & 31;
                ast(&KT[(tj * 32 + jl) * N + ti * 32 + il], kt[il * 33 + jl]);
            }
        }
    }
    gbar();

    // ---- phase 3: 20 iterations; wave owns row r; v/u staged to LDS via
    //      coherent loads, K/KT rows read through L2 (valid, never rewritten)
    const int r = bid * 4 + wid;
    const float4* Kr4  = (const float4*)(ws + WS_K  + (size_t)r * N);
    const float4* KTr4 = (const float4*)(ws + WS_KT + (size_t)r * N);
    float* u = ws + WS_U;
    float* v = ws + WS_V;
    const float4* sv4 = (const float4*)smem;
    #pragma unroll 1
    for (int it = 0; it < 20; ++it) {
        {   // stage v -> LDS (coherence-point reads)
            float t0 = ald(&v[tid]),       t1 = ald(&v[tid + 256]);
            float t2 = ald(&v[tid + 512]), t3 = ald(&v[tid + 768]);
            smem[tid] = t0; smem[tid + 256] = t1;
            smem[tid + 512] = t2; smem[tid + 768] = t3;
        }
        __syncthreads();
        float a = 0.f;
        #pragma unroll
        for (int j = lane; j < 256; j += 64) {
            const float4 kk = Kr4[j]; const float4 vv = sv4[j];
            a += kk.x * vv.x + kk.y * vv.y + kk.z * vv.z + kk.w * vv.w;
        }
        a = wsum(a);
        if (lane == 0) ast(&u[r], 1.0f / a);
        gbar();
        {   // stage u -> LDS
            float t0 = ald(&u[tid]),       t1 = ald(&u[tid + 256]);
            float t2 = ald(&u[tid + 512]), t3 = ald(&u[tid + 768]);
            smem[tid] = t0; smem[tid + 256] = t1;
            smem[tid + 512] = t2; smem[tid + 768] = t3;
        }
        __syncthreads();
        a = 0.f;
        #pragma unroll
        for (int j = lane; j < 256; j += 64) {
            const float4 kk = KTr4[j]; const float4 uu = sv4[j];
            a += kk.x * uu.x + kk.y * uu.y + kk.z * uu.z + kk.w * uu.w;
        }
        a = wsum(a);
        if (lane == 0) ast(&v[r], 1.0f / a);
        gbar();
    }

    // ---- phase 4: partial[bid] = sum over own rows of u_i K_ij v_j log K_ij
    {
        {   // stage final v -> LDS
            float t0 = ald(&v[tid]),       t1 = ald(&v[tid + 256]);
            float t2 = ald(&v[tid + 512]), t3 = ald(&v[tid + 768]);
            smem[tid] = t0; smem[tid + 256] = t1;
            smem[tid + 512] = t2; smem[tid + 768] = t3;
        }
        __syncthreads();
        const float* Kr = ws + WS_K + (size_t)r * N;
        float a = 0.f;
        for (int j = lane; j < N; j += 64) {
            const float k = Kr[j];
            a += k * smem[j] * logf(k);
        }
        a = wsum(a);
        if (lane == 0) smem[1024 + wid] = ald(&u[r]) * a;
        __syncthreads();
        if (tid == 0)
            ast(&ws[WS_P + bid],
                smem[1024] + smem[1025] + smem[1026] + smem[1027]);
    }
    gbar();

    // ---- phase 5: block 0 folds 256 partials -> scalar out ----
    if (bid == 0) {
        float acc = ald(&ws[WS_P + tid]);
        acc = wsum(acc);
        __syncthreads();
        if (lane == 0) smem[wid] = acc;
        __syncthreads();
        if (tid == 0)
            out[0] = -1e-4f * (smem[0] + smem[1] + smem[2] + smem[3]); // 1e-3*(-0.1)
    }
}

extern "C" void kernel_launch(void* const* d_in, const int* in_sizes, int n_in,
                              void* d_out, int out_size, void* d_ws, size_t ws_size,
                              hipStream_t stream) {
    const float* y_s = (const float*)d_in[0];
    const float* y_t = (const float*)d_in[1];
    float* out = (float*)d_out;
    float* ws  = (float*)d_ws;

    init_k<<<dim3(1),  dim3(256), 0, stream>>>(ws);
    sink_k<<<dim3(NB), dim3(256), 0, stream>>>(y_s, y_t, out, ws);
}